// Round 2
// baseline (461.532 us; speedup 1.0000x reference)
//
#include <hip/hip_runtime.h>

#define HIDDEN 1024
#define INTER  704
#define NEXP   32
#define TM     128

typedef __attribute__((ext_vector_type(8))) short bf16x8;
typedef __attribute__((ext_vector_type(4))) float f32x4;

__device__ __forceinline__ unsigned short f2bf(float f) {
    union { float f; unsigned u; } v; v.f = f;
    unsigned r = v.u + 0x7FFF + ((v.u >> 16) & 1);   // RNE
    return (unsigned short)(r >> 16);
}

__device__ __forceinline__ void load_lds16(const void* g, void* l) {
    __builtin_amdgcn_global_load_lds(
        (const __attribute__((address_space(1))) void*)g,
        (__attribute__((address_space(3))) void*)l, 16, 0, 0);
}

// map block m-index -> (expert, global row0, valid rows) over ragged groups
__device__ __forceinline__ bool map_tile(const int* s_tpe, int bm,
                                         int& row0, int& rows, int& e) {
    int start = 0, rem = bm;
    for (int i = 0; i < NEXP; ++i) {
        int g = s_tpe[i];
        int nt = (g + TM - 1) / TM;
        if (rem < nt) { row0 = start + rem * TM; rows = min(TM, g - rem * TM); e = i; return true; }
        rem -= nt; start += g;
    }
    return false;
}

// ---------------- prep: x fp32 -> bf16 (same layout) ----------------
__global__ void cvt_x(const float* __restrict__ x, unsigned short* __restrict__ xb, int n4) {
    int i = blockIdx.x * blockDim.x + threadIdx.x;
    for (; i < n4; i += gridDim.x * blockDim.x) {
        float4 v = ((const float4*)x)[i];
        uint2 o;
        o.x = (unsigned)f2bf(v.x) | ((unsigned)f2bf(v.y) << 16);
        o.y = (unsigned)f2bf(v.z) | ((unsigned)f2bf(v.w) << 16);
        ((uint2*)xb)[i] = o;
    }
}

// ---------------- prep: [e][R][C] f32 -> [e][C][R] bf16 ----------------
__global__ void transpose_cvt(const float* __restrict__ in, unsigned short* __restrict__ out,
                              int R, int C) {
    __shared__ float s[32][33];
    int e = blockIdx.z;
    int cb = blockIdx.x * 32;
    int rb = blockIdx.y * 32;
    int tx = threadIdx.x & 31, ty = threadIdx.x >> 5;   // ty 0..7
    const float* ip = in + (size_t)e * R * C;
    unsigned short* op = out + (size_t)e * C * R;
    #pragma unroll
    for (int j = 0; j < 4; ++j)
        s[ty + j * 8][tx] = ip[(size_t)(rb + ty + j * 8) * C + cb + tx];
    __syncthreads();
    #pragma unroll
    for (int j = 0; j < 4; ++j)
        op[(size_t)(cb + ty + j * 8) * R + rb + tx] = f2bf(s[tx][ty + j * 8]);
}

// ---------------- GEMM1 + SwiGLU:  h = silu(x@w1) * (x@w3) ----------------
// xb: [8192][1024] bf16; w1t: [E][1408][1024] bf16 (n-major, k-contiguous)
// block: 128 rows x (64 gate + 64 up cols), BK=64, 4 waves (each 32 rows x all cols)
__global__ __launch_bounds__(256)
void gemm1_swiglu(const unsigned short* __restrict__ xb, const int* __restrict__ tpe,
                  const unsigned short* __restrict__ w1t, unsigned short* __restrict__ h)
{
    __shared__ int s_tpe[NEXP];
    __shared__ __align__(16) unsigned short sA[128 * 64];   // [m][k], XOR-swizzled 16B blocks
    __shared__ __align__(16) unsigned short sB[128 * 64];   // [n][k]; n<64 gate, n>=64 up

    int t = threadIdx.x;
    if (t < NEXP) s_tpe[t] = tpe[t];
    __syncthreads();

    int row0, rows, e;
    if (!map_tile(s_tpe, blockIdx.x, row0, rows, e)) return;
    int jb = blockIdx.y;   // 0..10

    int wv = t >> 6, lane = t & 63, l16 = lane & 15, quad = lane >> 4;
    int srow = lane >> 3;          // 0..7 within 8-row staging chunk
    int sblk = lane & 7;           // 16B slot within 128B row

    const unsigned short* abase = xb + (size_t)row0 * HIDDEN;
    const unsigned short* bbase = w1t + (size_t)e * 1408 * HIDDEN;

    f32x4 accg[2][4], accu[2][4];
    #pragma unroll
    for (int i = 0; i < 2; i++)
        #pragma unroll
        for (int j = 0; j < 4; j++) { accg[i][j] = (f32x4)(0.f); accu[i][j] = (f32x4)(0.f); }

    int xk = l16 & 7;   // swizzle key for all fragment reads (row & 7 == l16 & 7)

    for (int ko = 0; ko < HIDDEN; ko += 64) {
        // ---- stage A: 4 chunks of 8 rows per wave, 16B/lane, swizzled ----
        #pragma unroll
        for (int i = 0; i < 4; ++i) {
            int r = wv * 32 + i * 8 + srow;
            int gblk = sblk ^ srow;
            const unsigned short* g = abase + (size_t)r * HIDDEN + ko + gblk * 8;
            if (r < rows) load_lds16(g, &sA[(wv * 32 + i * 8) * 64]);
        }
        // ---- stage B ----
        #pragma unroll
        for (int i = 0; i < 4; ++i) {
            int r = wv * 32 + i * 8 + srow;
            int gn = (r < 64) ? (jb * 64 + r) : (640 + jb * 64 + r);   // up rows at 704+
            int gblk = sblk ^ srow;
            const unsigned short* g = bbase + (size_t)gn * HIDDEN + ko + gblk * 8;
            load_lds16(g, &sB[(wv * 32 + i * 8) * 64]);
        }
        __syncthreads();   // drains vmcnt, publishes LDS

        #pragma unroll
        for (int kk = 0; kk < 2; ++kk) {
            int blk = ((kk << 2) + quad);
            bf16x8 a0 = *(const bf16x8*)&sA[(wv * 32 + l16) * 64 + (blk ^ xk) * 8];
            bf16x8 a1 = *(const bf16x8*)&sA[(wv * 32 + 16 + l16) * 64 + (blk ^ xk) * 8];
            #pragma unroll
            for (int ct = 0; ct < 4; ++ct) {
                bf16x8 bg = *(const bf16x8*)&sB[(ct * 16 + l16) * 64 + (blk ^ xk) * 8];
                bf16x8 bu = *(const bf16x8*)&sB[(64 + ct * 16 + l16) * 64 + (blk ^ xk) * 8];
                accg[0][ct] = __builtin_amdgcn_mfma_f32_16x16x32_bf16(a0, bg, accg[0][ct], 0, 0, 0);
                accg[1][ct] = __builtin_amdgcn_mfma_f32_16x16x32_bf16(a1, bg, accg[1][ct], 0, 0, 0);
                accu[0][ct] = __builtin_amdgcn_mfma_f32_16x16x32_bf16(a0, bu, accu[0][ct], 0, 0, 0);
                accu[1][ct] = __builtin_amdgcn_mfma_f32_16x16x32_bf16(a1, bu, accu[1][ct], 0, 0, 0);
            }
        }
        __syncthreads();   // all reads done before next stage
    }

    // ---- epilogue: SwiGLU, store h bf16 ----
    #pragma unroll
    for (int rt = 0; rt < 2; ++rt) {
        #pragma unroll
        for (int reg = 0; reg < 4; ++reg) {
            int rl = wv * 32 + rt * 16 + quad * 4 + reg;
            if (rl < rows) {
                size_t grow = (size_t)(row0 + rl);
                #pragma unroll
                for (int ct = 0; ct < 4; ++ct) {
                    int gc = jb * 64 + ct * 16 + l16;
                    float g = accg[rt][ct][reg];
                    float u = accu[rt][ct][reg];
                    float sv = g / (1.f + __expf(-g)) * u;
                    h[grow * INTER + gc] = f2bf(sv);
                }
            }
        }
    }
}

// ---------------- GEMM2:  out = h @ w2 ----------------
// h: [8192][704] bf16; w2t: [E][1024][704] bf16
// block: 128 x 128, 2x2 waves each 64x64 (4x4 16x16 tiles)
__global__ __launch_bounds__(256)
void gemm2(const unsigned short* __restrict__ h, const int* __restrict__ tpe,
           const unsigned short* __restrict__ w2t, float* __restrict__ out)
{
    __shared__ int s_tpe[NEXP];
    __shared__ __align__(16) unsigned short sA[128 * 64];
    __shared__ __align__(16) unsigned short sB[128 * 64];

    int t = threadIdx.x;
    if (t < NEXP) s_tpe[t] = tpe[t];
    __syncthreads();

    int row0, rows, e;
    if (!map_tile(s_tpe, blockIdx.x, row0, rows, e)) return;
    int nb = blockIdx.y;   // 0..7

    int wv = t >> 6, lane = t & 63, l16 = lane & 15, quad = lane >> 4;
    int wr = wv >> 1, wc = wv & 1;
    int srow = lane >> 3, sblk = lane & 7;

    const unsigned short* abase = h + (size_t)row0 * INTER;
    const unsigned short* bbase = w2t + (size_t)e * HIDDEN * INTER + (size_t)(nb * 128) * INTER;

    f32x4 acc[4][4];
    #pragma unroll
    for (int i = 0; i < 4; i++)
        #pragma unroll
        for (int j = 0; j < 4; j++) acc[i][j] = (f32x4)(0.f);

    int xk = l16 & 7;

    for (int ko = 0; ko < INTER; ko += 64) {   // 11 iters
        #pragma unroll
        for (int i = 0; i < 4; ++i) {
            int r = wv * 32 + i * 8 + srow;
            int gblk = sblk ^ srow;
            const unsigned short* g = abase + (size_t)r * INTER + ko + gblk * 8;
            if (r < rows) load_lds16(g, &sA[(wv * 32 + i * 8) * 64]);
        }
        #pragma unroll
        for (int i = 0; i < 4; ++i) {
            int r = wv * 32 + i * 8 + srow;
            int gblk = sblk ^ srow;
            const unsigned short* g = bbase + (size_t)r * INTER + ko + gblk * 8;
            load_lds16(g, &sB[(wv * 32 + i * 8) * 64]);
        }
        __syncthreads();

        #pragma unroll
        for (int kk = 0; kk < 2; ++kk) {
            int blk = ((kk << 2) + quad);
            bf16x8 a[4], b[4];
            #pragma unroll
            for (int rt = 0; rt < 4; ++rt)
                a[rt] = *(const bf16x8*)&sA[(wr * 64 + rt * 16 + l16) * 64 + (blk ^ xk) * 8];
            #pragma unroll
            for (int ct = 0; ct < 4; ++ct)
                b[ct] = *(const bf16x8*)&sB[(wc * 64 + ct * 16 + l16) * 64 + (blk ^ xk) * 8];
            #pragma unroll
            for (int rt = 0; rt < 4; ++rt)
                #pragma unroll
                for (int ct = 0; ct < 4; ++ct)
                    acc[rt][ct] = __builtin_amdgcn_mfma_f32_16x16x32_bf16(a[rt], b[ct], acc[rt][ct], 0, 0, 0);
        }
        __syncthreads();
    }

    #pragma unroll
    for (int rt = 0; rt < 4; ++rt) {
        #pragma unroll
        for (int reg = 0; reg < 4; ++reg) {
            int rl = wr * 64 + rt * 16 + quad * 4 + reg;
            if (rl < rows) {
                size_t grow = (size_t)(row0 + rl);
                #pragma unroll
                for (int ct = 0; ct < 4; ++ct)
                    out[grow * HIDDEN + nb * 128 + wc * 64 + ct * 16 + l16] = acc[rt][ct][reg];
            }
        }
    }
}

extern "C" void kernel_launch(void* const* d_in, const int* in_sizes, int n_in,
                              void* d_out, int out_size, void* d_ws, size_t ws_size,
                              hipStream_t stream) {
    const float* x    = (const float*)d_in[0];
    const int*   tpe  = (const int*)d_in[1];
    const float* w1w3 = (const float*)d_in[2];
    const float* w2   = (const float*)d_in[3];
    float* out = (float*)d_out;

    // ws layout (bf16 elems): h | xb | w1t ; w2t reuses xb+w1t region after gemm1.
    unsigned short* h   = (unsigned short*)d_ws;                 // 8192*704
    unsigned short* xb  = h + (size_t)8192 * INTER;              // 8192*1024
    unsigned short* w1t = xb + (size_t)8192 * HIDDEN;            // 32*1408*1024
    unsigned short* w2t = xb;                                    // 32*1024*704 (fits)

    hipLaunchKernelGGL(cvt_x, dim3(1024), dim3(256), 0, stream, x, xb, 8192 * HIDDEN / 4);
    hipLaunchKernelGGL(transpose_cvt, dim3(1408 / 32, 1024 / 32, NEXP), dim3(256), 0, stream,
                       w1w3, w1t, HIDDEN, 2 * INTER);
    hipLaunchKernelGGL(gemm1_swiglu, dim3(96, INTER / 64), dim3(256), 0, stream, xb, tpe, w1t, h);
    hipLaunchKernelGGL(transpose_cvt, dim3(1024 / 32, 704 / 32, NEXP), dim3(256), 0, stream,
                       w2, w2t, INTER, HIDDEN);
    hipLaunchKernelGGL(gemm2, dim3(96, HIDDEN / 128), dim3(256), 0, stream, h, tpe, w2t, out);
}